// Round 1
// 738.727 us; speedup vs baseline: 1.0353x; 1.0353x over previous
//
#include <hip/hip_runtime.h>
#include <math.h>

// AttentionAggregator2 fused kernels for MI355X (gfx950).
// v2: latency-bound fix. Old single kernel was 4-barrier serial chain at
// 2 blocks/CU (60 KB LDS) with both pipes idle (HBM 18.6%, VALU 29%).
// New structure:
//   pre_kernel : everything x-dependent (t1, u = t1@M, out[:, :128]) via MFMA,
//                u parked in out[:, 128:160] (overwritten by epilogue later).
//   attn_kernel: one wave per node, zero LDS staging, in-register softmax,
//                ne re-read for aggregation served by L2 (reuse dist ~1 us),
//                single barrier only for the agg@Wfn MFMA epilogue.
// Key algebra (unchanged): ws[n,k] = tanh(ne@W2a) . u[n], u[n] = M^T tanh(x@W1a),
// M = W1b @ W2b^T.

typedef _Float16 half_t;
typedef __attribute__((ext_vector_type(4))) _Float16 half4_t;
typedef __attribute__((ext_vector_type(8))) _Float16 half8_t;
typedef __attribute__((ext_vector_type(4))) float f32x4;

#define NN   50000
#define GK   16     // neighbors per node
#define DIN  128
#define DED  64
#define DNE  192    // DIN + DED

// workspace byte offsets (written fresh by setup_kernel every launch)
#define WS_M    0        // 32x32 f32: M = W1b @ W2b^T
#define WS_W1A  4096     // 2 tiles * 4 ksteps * 64 lanes * 8 halfs
#define WS_W2A  12288    // 2 * 6 * 512
#define WS_WFX  24576    // 8 * 4 * 512
#define WS_WFN  57344    // 8 * 6 * 512   (total 106496 B of d_ws used)

// Pre-swizzle weight matrix W[K x ncol] into MFMA B-fragment order:
// frag element ((t*S+s)*64 + lane)*8 + j  <=  W[32s + (lane>>4)*8 + j][16t + (lane&15)]
__device__ __forceinline__ void swz(const float* __restrict__ W, int ncol, int S,
                                    half_t* __restrict__ dst, int tid, int nth) {
  int T = ncol >> 4;
  int total = T * S * 512;
  for (int i = tid; i < total; i += nth) {
    int j = i & 7;
    int l = (i >> 3) & 63;
    int rest = i >> 9;
    int s = rest % S;
    int t = rest / S;
    int k = 32 * s + (l >> 4) * 8 + j;
    int n = 16 * t + (l & 15);
    dst[i] = (half_t)W[k * ncol + n];
  }
}

__global__ void setup_kernel(const float* __restrict__ W1a, const float* __restrict__ W1b,
                             const float* __restrict__ W2a, const float* __restrict__ W2b,
                             const float* __restrict__ Wfx, const float* __restrict__ Wfn,
                             unsigned char* __restrict__ ws) {
  int tid = blockIdx.x * blockDim.x + threadIdx.x;
  int nth = gridDim.x * blockDim.x;
  float* Mm = (float*)(ws + WS_M);
  for (int i = tid; i < 1024; i += nth) {        // M[a][h] = sum_h2 W1b[a][h2]*W2b[h][h2]
    int a = i >> 5, h = i & 31;
    float acc = 0.f;
    for (int h2 = 0; h2 < 32; ++h2)
      acc = fmaf(W1b[a * 32 + h2], W2b[h * 32 + h2], acc);
    Mm[i] = acc;
  }
  swz(W1a, 32, 4, (half_t*)(ws + WS_W1A), tid, nth);
  swz(W2a, 32, 6, (half_t*)(ws + WS_W2A), tid, nth);
  swz(Wfx, 128, 4, (half_t*)(ws + WS_WFX), tid, nth);
  swz(Wfn, 128, 6, (half_t*)(ws + WS_WFN), tid, nth);
}

__device__ __forceinline__ half8_t cvt8(float4 a, float4 b) {
  half8_t r;
  r[0] = (half_t)a.x; r[1] = (half_t)a.y; r[2] = (half_t)a.z; r[3] = (half_t)a.w;
  r[4] = (half_t)b.x; r[5] = (half_t)b.y; r[6] = (half_t)b.z; r[7] = (half_t)b.w;
  return r;
}

__device__ __forceinline__ float elu(float v) { return v > 0.f ? v : expm1f(v); }

// ---------------------------------------------------------------------------
// pre_kernel: per wave, 16 nodes. Computes t1 = tanh(x@W1a), u = t1@M,
// outx = elu(x@Wfx). Writes out[n][0:128] = outx, out[n][128:160] = u (f32,
// temporary storage; attn_kernel reads it pre-barrier and overwrites later).
// ---------------------------------------------------------------------------
__global__ __launch_bounds__(256, 4)
void pre_kernel(const float* __restrict__ x, const unsigned char* __restrict__ ws,
                float* __restrict__ out) {
  __shared__ float t1L[64][33];
  const int tid = threadIdx.x;
  const int wave = tid >> 6, lane = tid & 63;
  const int l15 = lane & 15, q = lane >> 4;
  const int nb0 = blockIdx.x * 64;
  const int n0 = nb0 + wave * 16;
  const float* Mm = (const float*)(ws + WS_M);
  const half_t* w1a = (const half_t*)(ws + WS_W1A);
  const half_t* wfx = (const half_t*)(ws + WS_WFX);

  int row = n0 + l15; if (row >= NN) row = NN - 1;   // clamped tail
  const float* xrow = x + (size_t)row * DIN;
  half8_t Ax[4];
  f32x4 t0acc = {0.f, 0.f, 0.f, 0.f}, t1acc = {0.f, 0.f, 0.f, 0.f};
#pragma unroll
  for (int s = 0; s < 4; ++s) {
    float4 a0 = *(const float4*)(xrow + 32 * s + 8 * q);
    float4 a1 = *(const float4*)(xrow + 32 * s + 8 * q + 4);
    Ax[s] = cvt8(a0, a1);
    half8_t B0 = *(const half8_t*)(w1a + ((size_t)(0 * 4 + s) * 64 + lane) * 8);
    half8_t B1 = *(const half8_t*)(w1a + ((size_t)(1 * 4 + s) * 64 + lane) * 8);
    t0acc = __builtin_amdgcn_mfma_f32_16x16x32_f16(Ax[s], B0, t0acc, 0, 0, 0);
    t1acc = __builtin_amdgcn_mfma_f32_16x16x32_f16(Ax[s], B1, t1acc, 0, 0, 0);
  }
#pragma unroll
  for (int r = 0; r < 4; ++r) {                      // C: col=l15, row=4q+r
    t1L[wave * 16 + 4 * q + r][l15]      = tanhf(t0acc[r]);
    t1L[wave * 16 + 4 * q + r][16 + l15] = tanhf(t1acc[r]);
  }
  __syncthreads();

  // u[g][h] = sum_a t1[g][a] * M[a][h]; 64 nodes x 32 h / 256 threads
#pragma unroll
  for (int i = 0; i < 8; ++i) {
    int idx = i * 256 + tid;
    int g = idx >> 5, h = idx & 31;
    float acc = 0.f;
#pragma unroll
    for (int a = 0; a < 32; ++a)
      acc = fmaf(t1L[g][a], Mm[a * 32 + h], acc);
    int n = nb0 + g;
    if (n < NN) out[(size_t)n * 256 + 128 + h] = acc;   // u parked in out
  }

  // outx = elu(x @ Wfx), col tile t
#pragma unroll
  for (int t = 0; t < 8; ++t) {
    f32x4 acc = {0.f, 0.f, 0.f, 0.f};
#pragma unroll
    for (int s = 0; s < 4; ++s) {
      half8_t B = *(const half8_t*)(wfx + ((size_t)(t * 4 + s) * 64 + lane) * 8);
      acc = __builtin_amdgcn_mfma_f32_16x16x32_f16(Ax[s], B, acc, 0, 0, 0);
    }
#pragma unroll
    for (int r = 0; r < 4; ++r) {
      int m = n0 + 4 * q + r;
      if (m < NN) out[(size_t)m * 256 + t * 16 + l15] = elu(acc[r]);
    }
  }
}

// ---------------------------------------------------------------------------
// attn_kernel: one wave per node (8 waves/block), no LDS staging.
// score MFMA from global f32 -> f16 frags; in-register masked softmax;
// aggregation re-reads ne from L2 (coalesced 256B rows); single barrier to
// share 8 agg rows (f16 LDS) for the agg@Wfn MFMA epilogue.
// ---------------------------------------------------------------------------
__global__ __launch_bounds__(512, 6)
void attn_kernel(const float* __restrict__ neibs, const float* __restrict__ edge,
                 const float* __restrict__ mask, const unsigned char* __restrict__ ws,
                 float* __restrict__ out) {
  __shared__ __align__(16) half_t aggL[16][200];   // 6400 B; rows 8..15 stay 0
  const int tid = threadIdx.x;
  const int wave = tid >> 6, lane = tid & 63;
  const int l15 = lane & 15, q = lane >> 4;
  const int n = blockIdx.x * 8 + wave;             // 6250 * 8 = 50000 exact
  const half_t* w2a = (const half_t*)(ws + WS_W2A);
  const half_t* wfn = (const half_t*)(ws + WS_WFN);

  // zero rows 8..15 only (disjoint from rows 0..7 written by waves -> no race)
  for (int i = tid; i < 800; i += 512)
    ((unsigned int*)&aggL[8][0])[i] = 0u;

  // ---- scores: S = tanh(ne @ W2a) [16 x 32]; A rows = neighbors k = l15 ----
  f32x4 acc0 = {0.f, 0.f, 0.f, 0.f}, acc1 = {0.f, 0.f, 0.f, 0.f};
  const float* nbase = neibs + (size_t)n * (GK * DIN);
  const float* ebase = edge + (size_t)n * (GK * DED);
  const float* nrow = nbase + l15 * DIN;
  const float* erow = ebase + l15 * DED;
#pragma unroll
  for (int s = 0; s < 4; ++s) {
    float4 a0 = *(const float4*)(nrow + 32 * s + 8 * q);
    float4 a1 = *(const float4*)(nrow + 32 * s + 8 * q + 4);
    half8_t A = cvt8(a0, a1);
    half8_t B0 = *(const half8_t*)(w2a + ((size_t)(0 * 6 + s) * 64 + lane) * 8);
    half8_t B1 = *(const half8_t*)(w2a + ((size_t)(1 * 6 + s) * 64 + lane) * 8);
    acc0 = __builtin_amdgcn_mfma_f32_16x16x32_f16(A, B0, acc0, 0, 0, 0);
    acc1 = __builtin_amdgcn_mfma_f32_16x16x32_f16(A, B1, acc1, 0, 0, 0);
  }
#pragma unroll
  for (int s = 0; s < 2; ++s) {
    float4 a0 = *(const float4*)(erow + 32 * s + 8 * q);
    float4 a1 = *(const float4*)(erow + 32 * s + 8 * q + 4);
    half8_t A = cvt8(a0, a1);
    half8_t B0 = *(const half8_t*)(w2a + ((size_t)(0 * 6 + 4 + s) * 64 + lane) * 8);
    half8_t B1 = *(const half8_t*)(w2a + ((size_t)(1 * 6 + 4 + s) * 64 + lane) * 8);
    acc0 = __builtin_amdgcn_mfma_f32_16x16x32_f16(A, B0, acc0, 0, 0, 0);
    acc1 = __builtin_amdgcn_mfma_f32_16x16x32_f16(A, B1, acc1, 0, 0, 0);
  }

  // u from pre_kernel (parked at out[n][128:160]); 64B broadcast load
  const float u0 = out[(size_t)n * 256 + 128 + l15];
  const float u1 = out[(size_t)n * 256 + 144 + l15];

  // s[k] = sum_h tanh(S[k][h]) * u[h]; lane holds col h=l15(+16), rows k=4q+r
  float sv[4];
#pragma unroll
  for (int r = 0; r < 4; ++r)
    sv[r] = tanhf(acc0[r]) * u0 + tanhf(acc1[r]) * u1;
#pragma unroll
  for (int off = 1; off <= 8; off <<= 1)
#pragma unroll
    for (int r = 0; r < 4; ++r)
      sv[r] += __shfl_xor(sv[r], off);   // reduce over 16 cols; k=4q+r replicated

  // ---- masked softmax fully in registers (all 64 lanes participate) ----
  float e[4];
  float mx = -3.4e38f;
#pragma unroll
  for (int r = 0; r < 4; ++r) {
    sv[r] -= 9999999.0f * mask[(size_t)n * GK + 4 * q + r];
    mx = fmaxf(mx, sv[r]);
  }
  mx = fmaxf(mx, __shfl_xor(mx, 16));
  mx = fmaxf(mx, __shfl_xor(mx, 32));
  float sm = 0.f;
#pragma unroll
  for (int r = 0; r < 4; ++r) { e[r] = expf(sv[r] - mx); sm += e[r]; }
  sm += __shfl_xor(sm, 16);
  sm += __shfl_xor(sm, 32);
  const float rs = 1.0f / sm;
#pragma unroll
  for (int r = 0; r < 4; ++r) e[r] *= rs;   // weight for k=4q+r

  // ---- aggregation: lane owns d = lane, 64+lane, edge lane; ne from L2 ----
  float a0 = 0.f, a1 = 0.f, a2 = 0.f;
#pragma unroll
  for (int k = 0; k < GK; ++k) {
    float wv = __shfl(e[k & 3], (k & 12) << 2);   // lane 16*(k>>2) holds k's weight
    a0 = fmaf(wv, nbase[k * DIN + lane], a0);
    a1 = fmaf(wv, nbase[k * DIN + 64 + lane], a1);
    a2 = fmaf(wv, ebase[k * DED + lane], a2);
  }
  aggL[wave][lane] = (half_t)a0;
  aggL[wave][64 + lane] = (half_t)a1;
  aggL[wave][128 + lane] = (half_t)a2;
  __syncthreads();

  // ---- epilogue: out[:,128:] = elu(agg @ Wfn); wave = col tile ----
  f32x4 accn = {0.f, 0.f, 0.f, 0.f};
#pragma unroll
  for (int s = 0; s < 6; ++s) {
    half8_t A = *(const half8_t*)(&aggL[l15][32 * s + 8 * q]);
    half8_t B = *(const half8_t*)(wfn + ((size_t)(wave * 6 + s) * 64 + lane) * 8);
    accn = __builtin_amdgcn_mfma_f32_16x16x32_f16(A, B, accn, 0, 0, 0);
  }
  const size_t ob = (size_t)blockIdx.x * 8 * 256;
#pragma unroll
  for (int r = 0; r < 4; ++r) {
    int m = 4 * q + r;                   // C row = node (rows 8..15 are zeros)
    if (m < 8)
      out[ob + (size_t)m * 256 + 128 + wave * 16 + l15] = elu(accn[r]);
  }
}

extern "C" void kernel_launch(void* const* d_in, const int* in_sizes, int n_in,
                              void* d_out, int out_size, void* d_ws, size_t ws_size,
                              hipStream_t stream) {
  const float* x     = (const float*)d_in[0];
  const float* neibs = (const float*)d_in[1];
  const float* edge  = (const float*)d_in[2];
  const float* mask  = (const float*)d_in[3];
  const float* W1a   = (const float*)d_in[4];
  const float* W1b   = (const float*)d_in[5];
  const float* W2a   = (const float*)d_in[6];
  const float* W2b   = (const float*)d_in[7];
  const float* Wfx   = (const float*)d_in[8];
  const float* Wfn   = (const float*)d_in[9];
  float* out = (float*)d_out;
  unsigned char* ws = (unsigned char*)d_ws;

  hipLaunchKernelGGL(setup_kernel, dim3(64), dim3(256), 0, stream,
                     W1a, W1b, W2a, W2b, Wfx, Wfn, ws);
  hipLaunchKernelGGL(pre_kernel, dim3((NN + 63) / 64), dim3(256), 0, stream,
                     x, ws, out);
  hipLaunchKernelGGL(attn_kernel, dim3(NN / 8), dim3(512), 0, stream,
                     neibs, edge, mask, ws, out);
}